// Round 9
// baseline (1890.880 us; speedup 1.0000x reference)
//
#include <hip/hip_runtime.h>
#include <math.h>

#define NB 256
#define IMG 256
#define GSZ 64
#define HID 512
#define NSTEP 16
#define KTOT 4608            // 4096 (x) + 512 (Hx)
#define SPLITK 8
#define KCHUNK 576           // KTOT / SPLITK
#define KSTEPS 18            // KCHUNK / 32
#define SP 40                // img-stage / Fw-chunk pitch (u16)
#define TP 72                // t1T / Fh chunk pitch (u16)

typedef unsigned short u16;
typedef unsigned long long u64;
typedef __attribute__((ext_vector_type(8))) short s16x8;   // 8 bf16
typedef __attribute__((ext_vector_type(4))) float f32x4;

__device__ inline u16 f2bf(float f) {           // round-to-nearest-even bf16
    unsigned u = __float_as_uint(f);
    unsigned r = u + 0x7fffu + ((u >> 16) & 1u);
    return (u16)(r >> 16);
}
__device__ inline float bf2f(u16 h) { return __uint_as_float((unsigned)h << 16); }
__device__ inline float sigm(float v) { return 1.0f / (1.0f + expf(-v)); }

// L2-bypass (agent/L3-coherent) 16B load as two 8B relaxed atomics.
__device__ inline s16x8 ld_l3_16(const u16* p) {
    union { s16x8 v; u64 q[2]; } u;
    u.q[0] = __hip_atomic_load((const u64*)p,       __ATOMIC_RELAXED, __HIP_MEMORY_SCOPE_AGENT);
    u.q[1] = __hip_atomic_load((const u64*)(p + 4), __ATOMIC_RELAXED, __HIP_MEMORY_SCOPE_AGENT);
    return u.v;
}
__device__ inline float ld_l3_f32(const float* p) {
    return __hip_atomic_load(p, __ATOMIC_RELAXED, __HIP_MEMORY_SCOPE_AGENT);
}

// software grid barrier: bar[0]=release gen, bar[1..256]=per-block arrive gen.
// Arrival = RELEASE store (s_waitcnt + wbl2 of the block's few dirty lines + sc1
// flag store) -> all plain-stored shared data reaches L3 before the flag does.
// Spins are RELAXED (no cache ops). NO ACQUIRE anywhere: consumers read shared
// data via sc1 (L2-bypass) loads from L3, so no invalidate is needed and the
// L2s keep weights/images warm across barriers (r8's acquire-inv wiped them).
__device__ inline void gridbar(int* bar, int gen) {
    __syncthreads();
    const int b = blockIdx.x, t = threadIdx.x;
    if (b == 0) {
        if (t > 0) {          // thread t watches block t's arrive flag
            while (__hip_atomic_load(&bar[1 + t], __ATOMIC_RELAXED,
                                     __HIP_MEMORY_SCOPE_AGENT) < gen)
                __builtin_amdgcn_s_sleep(4);
        }
        __syncthreads();      // all arrivals observed (their data already in L3)
        if (t == 0)
            __hip_atomic_store(&bar[0], gen, __ATOMIC_RELEASE,
                               __HIP_MEMORY_SCOPE_AGENT);   // flushes block 0's data too
    } else {
        if (t == 0) {
            __hip_atomic_store(&bar[1 + b], gen, __ATOMIC_RELEASE,
                               __HIP_MEMORY_SCOPE_AGENT);   // publishes this block's writes
            while (__hip_atomic_load(&bar[0], __ATOMIC_RELAXED,
                                     __HIP_MEMORY_SCOPE_AGENT) < gen)
                __builtin_amdgcn_s_sleep(4);
        }
        __syncthreads();
    }
    asm volatile("" ::: "memory");   // compiler: no hoisting of loads above the spin
}

__global__ __launch_bounds__(256, 2) void k_all(
    const float* __restrict__ imgs, const float* __restrict__ W_ih,
    const float* __restrict__ W_hh, const float* __restrict__ b_ih,
    const float* __restrict__ b_hh, const float* __restrict__ W_g,
    const float* __restrict__ b_g,
    int* __restrict__ bar,
    u16* __restrict__ wc_hi, u16* __restrict__ wc_lo,
    u16* __restrict__ xcat_hi, u16* __restrict__ xcat_lo,
    float* __restrict__ part, float* __restrict__ out)
{
    // 51,200 B overlaid static LDS (+ small scratch) -- fits default 64 KB
    __shared__ __align__(16) u16 sm[25600];
    __shared__ float invW[64];
    __shared__ float invA[64];
    __shared__ float red[12];
    // phase-1 overlay
    u16* AstH = sm;            // [256][SP] img chunk hi
    u16* AstL = sm + 10240;    // [256][SP] img chunk lo
    u16* FwcH = sm + 20480;    // [64][SP]  Fw chunk hi
    u16* FwcL = sm + 23040;    // [64][SP]  Fw chunk lo
    // phase-2 overlay
    u16* t1TH = sm;            // [64][TP]  t1T chunk hi
    u16* t1TL = sm + 4608;
    u16* FhcH = sm + 9216;     // [64][TP]  Fh chunk hi
    u16* FhcL = sm + 13824;
    // G-phase overlay
    u16 (*gsm)[128][40] = (u16 (*)[128][40])sm;

    const int b = blockIdx.x, t = threadIdx.x;
    const int lane = t & 63, wv = t >> 6;
    const int fr = lane & 15, kg = lane >> 4;

    // persistent LSTM state: units t and t+256 of batch b
    float hx0 = 0.f, hx1 = 0.f, cx0 = 0.f, cx1 = 0.f;

    // G-phase tiling (constant per block)
    const int mbG = b & 1;
    const int nbG = (b >> 1) & 15;
    const int kcG = b >> 5;
    const int m0G = mbG * 128, n0G = nbG * 128, k0G = kcG * KCHUNK;
    const int wmG = wv >> 1, wnG = wv & 1;
    const u16* gsrc0[8];       // start-of-chunk source pointers
    u16* gdst[8];
    #pragma unroll
    for (int q = 0; q < 8; ++q) {
        const int idx = ((q * 256 + t) & 511);
        const int row = idx >> 2;
        const int ko = (idx & 3) * 8;
        const int mat = q >> 1;
        const u16* gbase;
        if (mat == 0)      gbase = xcat_hi + (size_t)(m0G + row) * KTOT;
        else if (mat == 1) gbase = xcat_lo + (size_t)(m0G + row) * KTOT;
        else if (mat == 2) gbase = wc_hi + (size_t)(n0G + row) * KTOT;
        else               gbase = wc_lo + (size_t)(n0G + row) * KTOT;
        gsrc0[q] = gbase + k0G + ko;
        gdst[q] = &gsm[mat][row][ko];
    }

    // ---------- weight split phase (wc = [W_ih | W_hh] hi/lo) ----------
    // plain stores; flushed to L3 by this block's gridbar(1) RELEASE.
    {
        const int nchunk = 2048 * KTOT / 4;      // 2,359,296
        for (int c = b * 256 + t; c < nchunk; c += 65536) {
            const int j = c / (KTOT / 4);
            const int k = (c - j * (KTOT / 4)) * 4;
            float4 v;
            if (k < 4096) v = *(const float4*)&W_ih[(size_t)j * 4096 + k];
            else          v = *(const float4*)&W_hh[(size_t)j * 512 + (k - 4096)];
            float f[4] = {v.x, v.y, v.z, v.w};
            u16 hi[4], lo[4];
            #pragma unroll
            for (int i = 0; i < 4; ++i) {
                hi[i] = f2bf(f[i]);
                lo[i] = f2bf(f[i] - bf2f(hi[i]));
            }
            const size_t o = (size_t)j * KTOT + k;
            *(ushort4*)&wc_hi[o] = make_ushort4(hi[0], hi[1], hi[2], hi[3]);
            *(ushort4*)&wc_lo[o] = make_ushort4(lo[0], lo[1], lo[2], lo[3]);
        }
    }
    // first wc read is in G(0), after the first grid barrier (race-free)

    for (int step = 0; step < NSTEP; ++step) {
        // ========== LSTM update from previous step's partials ==========
        if (step == 0) {
            const size_t o = (size_t)b * KTOT + 4096 + t;
            xcat_hi[o] = 0;       xcat_lo[o] = 0;
            xcat_hi[o + 256] = 0; xcat_lo[o + 256] = 0;
        } else {
            #pragma unroll
            for (int half = 0; half < 2; ++half) {
                const int u = t + half * 256;
                float gi = b_ih[u] + b_hh[u];
                float gf = b_ih[HID + u] + b_hh[HID + u];
                float gg = b_ih[2 * HID + u] + b_hh[2 * HID + u];
                float go = b_ih[3 * HID + u] + b_hh[3 * HID + u];
                const float* pb = part + (size_t)b * 2048;
                #pragma unroll
                for (int kc = 0; kc < SPLITK; ++kc) {
                    const float* p = pb + (size_t)kc * (256 * 2048);
                    gi += ld_l3_f32(p + u);
                    gf += ld_l3_f32(p + HID + u);
                    gg += ld_l3_f32(p + 2 * HID + u);
                    go += ld_l3_f32(p + 3 * HID + u);
                }
                float co = half ? cx1 : cx0;
                float c = sigm(gf) * co + sigm(gi) * tanhf(gg);
                float h = sigm(go) * tanhf(c);
                if (half) { cx1 = c; hx1 = h; } else { cx0 = c; hx0 = h; }
                u16 hh = f2bf(h);
                xcat_hi[(size_t)b * KTOT + 4096 + u] = hh;
                xcat_lo[(size_t)b * KTOT + 4096 + u] = f2bf(h - bf2f(hh));
            }
        }
        // ========== params: gp = tanh(Hx @ W_g^T + b_g) ==========
        float s0 = hx0 * W_g[t] + hx1 * W_g[t + 256];
        float s1 = hx0 * W_g[HID + t] + hx1 * W_g[HID + t + 256];
        float s2 = hx0 * W_g[2 * HID + t] + hx1 * W_g[2 * HID + t + 256];
        for (int off = 32; off; off >>= 1) {
            s0 += __shfl_xor(s0, off, 64);
            s1 += __shfl_xor(s1, off, 64);
            s2 += __shfl_xor(s2, off, 64);
        }
        __syncthreads();
        if (lane == 0) { red[wv * 3 + 0] = s0; red[wv * 3 + 1] = s1; red[wv * 3 + 2] = s2; }
        __syncthreads();
        s0 = red[0] + red[3] + red[6] + red[9];
        s1 = red[1] + red[4] + red[7] + red[10];
        s2 = red[2] + red[5] + red[8] + red[11];
        const float g0 = tanhf(s0 + b_g[0]);
        const float g1 = tanhf(s1 + b_g[1]);
        const float g2 = tanhf(s2 + b_g[2]);
        const float ad = fabsf(g2);
        const float ch = 127.5f * (g0 + 1.0f);
        const float cw = 127.5f * (g1 + 1.0f);
        const float dl = 4.0f * (1.0f - ad);
        const float gm = expf(1.0f - 2.0f * ad);
        const float ig = 1.0f / gm;
        const float coef = 1.0f / (3.14159265358979323846f * gm);

        // ========== glimpse phase 1: t1T[gw][h] = sum_w Fw[gw][w]*img[h][w] ==========
        const int fwr = t >> 2;              // gw row this thread fills
        const int fwc = (t & 3) * 8;         // col offset within 32-chunk
        const float rcw = cw + dl * ((float)fwr - 31.5f);
        float rsW = 0.f;

        const float* imgp = imgs + (size_t)(b * 2 + (step & 1)) * (IMG * IMG);
        int rowA[8], coA[8];
        float4 pf[8];
        #pragma unroll
        for (int q = 0; q < 8; ++q) {
            const int c = q * 256 + t;
            rowA[q] = c >> 3;
            coA[q]  = (c & 7) * 4;
            pf[q] = *(const float4*)&imgp[rowA[q] * IMG + coA[q]];
        }
        f32x4 acc[4][4];
        #pragma unroll
        for (int mi = 0; mi < 4; ++mi)
            #pragma unroll
            for (int ni = 0; ni < 4; ++ni) acc[mi][ni] = (f32x4)(0.f);

        for (int ks = 0; ks < 8; ++ks) {
            __syncthreads();
            #pragma unroll
            for (int q = 0; q < 8; ++q) {
                float f[4] = {pf[q].x, pf[q].y, pf[q].z, pf[q].w};
                u16 hh[4], ll[4];
                #pragma unroll
                for (int j = 0; j < 4; ++j) {
                    hh[j] = f2bf(f[j]);
                    ll[j] = f2bf(f[j] - bf2f(hh[j]));
                }
                *(ushort4*)&AstH[rowA[q] * SP + coA[q]] = make_ushort4(hh[0], hh[1], hh[2], hh[3]);
                *(ushort4*)&AstL[rowA[q] * SP + coA[q]] = make_ushort4(ll[0], ll[1], ll[2], ll[3]);
            }
            {
                u16 hh[8], ll[8];
                #pragma unroll
                for (int j = 0; j < 8; ++j) {
                    float u = ((float)(ks * 32 + fwc + j) - rcw) * ig;
                    float val = coef / (1.0f + u * u);
                    rsW += val;
                    hh[j] = f2bf(val);
                    ll[j] = f2bf(val - bf2f(hh[j]));
                }
                *(ushort4*)&FwcH[fwr * SP + fwc]     = make_ushort4(hh[0], hh[1], hh[2], hh[3]);
                *(ushort4*)&FwcH[fwr * SP + fwc + 4] = make_ushort4(hh[4], hh[5], hh[6], hh[7]);
                *(ushort4*)&FwcL[fwr * SP + fwc]     = make_ushort4(ll[0], ll[1], ll[2], ll[3]);
                *(ushort4*)&FwcL[fwr * SP + fwc + 4] = make_ushort4(ll[4], ll[5], ll[6], ll[7]);
            }
            __syncthreads();
            if (ks < 7) {
                #pragma unroll
                for (int q = 0; q < 8; ++q)
                    pf[q] = *(const float4*)&imgp[rowA[q] * IMG + (ks + 1) * 32 + coA[q]];
            }
            s16x8 ah[4], al[4], bh[4], bl[4];
            #pragma unroll
            for (int mi = 0; mi < 4; ++mi) {
                const int r = mi * 16 + fr;
                ah[mi] = *(const s16x8*)&FwcH[r * SP + kg * 8];
                al[mi] = *(const s16x8*)&FwcL[r * SP + kg * 8];
            }
            #pragma unroll
            for (int ni = 0; ni < 4; ++ni) {
                const int r = wv * 64 + ni * 16 + fr;
                bh[ni] = *(const s16x8*)&AstH[r * SP + kg * 8];
                bl[ni] = *(const s16x8*)&AstL[r * SP + kg * 8];
            }
            #pragma unroll
            for (int mi = 0; mi < 4; ++mi)
                #pragma unroll
                for (int ni = 0; ni < 4; ++ni) {
                    acc[mi][ni] = __builtin_amdgcn_mfma_f32_16x16x32_bf16(ah[mi], bh[ni], acc[mi][ni], 0, 0, 0);
                    acc[mi][ni] = __builtin_amdgcn_mfma_f32_16x16x32_bf16(ah[mi], bl[ni], acc[mi][ni], 0, 0, 0);
                    acc[mi][ni] = __builtin_amdgcn_mfma_f32_16x16x32_bf16(al[mi], bh[ni], acc[mi][ni], 0, 0, 0);
                }
        }
        // invW reduce (4 consecutive lanes per row) and scale accumulators
        rsW += __shfl_xor(rsW, 1, 64);
        rsW += __shfl_xor(rsW, 2, 64);
        if ((t & 3) == 0) invW[fwr] = 1.0f / (rsW + 1e-4f);
        __syncthreads();
        #pragma unroll
        for (int mi = 0; mi < 4; ++mi) {
            float w4[4];
            #pragma unroll
            for (int r = 0; r < 4; ++r) w4[r] = invW[mi * 16 + kg * 4 + r];
            #pragma unroll
            for (int ni = 0; ni < 4; ++ni)
                #pragma unroll
                for (int r = 0; r < 4; ++r) acc[mi][ni][r] *= w4[r];
        }

        // ========== glimpse phase 2: x[gh][gw] = invA[gh]*sum_h Fh[gh][h]*t1T[gw][h] ==========
        f32x4 xacc[4];
        #pragma unroll
        for (int ni = 0; ni < 4; ++ni) xacc[ni] = (f32x4)(0.f);
        const int fhr = t >> 2;              // gh row this thread fills
        const int fhc = (t & 3) * 16;        // col offset within 64-chunk
        const float rch = ch + dl * ((float)fhr - 31.5f);
        float rsA = 0.f;

        for (int p = 0; p < 4; ++p) {
            __syncthreads();
            #pragma unroll
            for (int blk = 0; blk < 4; ++blk) {
                u16 hh[4], ll[4];
                #pragma unroll
                for (int j = 0; j < 4; ++j) {
                    float u = ((float)(p * 64 + fhc + blk * 4 + j) - rch) * ig;
                    float val = coef / (1.0f + u * u);
                    rsA += val;
                    hh[j] = f2bf(val);
                    ll[j] = f2bf(val - bf2f(hh[j]));
                }
                *(ushort4*)&FhcH[fhr * TP + fhc + blk * 4] = make_ushort4(hh[0], hh[1], hh[2], hh[3]);
                *(ushort4*)&FhcL[fhr * TP + fhc + blk * 4] = make_ushort4(ll[0], ll[1], ll[2], ll[3]);
            }
            if (wv == p) {
                #pragma unroll
                for (int mi = 0; mi < 4; ++mi)
                    #pragma unroll
                    for (int ni = 0; ni < 4; ++ni)
                        #pragma unroll
                        for (int r = 0; r < 4; ++r) {
                            const int row = mi * 16 + kg * 4 + r;   // gw
                            const int col = ni * 16 + fr;           // local h
                            float v = acc[mi][ni][r];
                            u16 hv = f2bf(v);
                            t1TH[row * TP + col] = hv;
                            t1TL[row * TP + col] = f2bf(v - bf2f(hv));
                        }
            }
            __syncthreads();
            #pragma unroll
            for (int k2 = 0; k2 < 2; ++k2) {
                const int ra = wv * 16 + fr;
                s16x8 a2h = *(const s16x8*)&FhcH[ra * TP + k2 * 32 + kg * 8];
                s16x8 a2l = *(const s16x8*)&FhcL[ra * TP + k2 * 32 + kg * 8];
                #pragma unroll
                for (int ni = 0; ni < 4; ++ni) {
                    const int rb = ni * 16 + fr;
                    s16x8 b2h = *(const s16x8*)&t1TH[rb * TP + k2 * 32 + kg * 8];
                    s16x8 b2l = *(const s16x8*)&t1TL[rb * TP + k2 * 32 + kg * 8];
                    xacc[ni] = __builtin_amdgcn_mfma_f32_16x16x32_bf16(a2h, b2h, xacc[ni], 0, 0, 0);
                    xacc[ni] = __builtin_amdgcn_mfma_f32_16x16x32_bf16(a2h, b2l, xacc[ni], 0, 0, 0);
                    xacc[ni] = __builtin_amdgcn_mfma_f32_16x16x32_bf16(a2l, b2h, xacc[ni], 0, 0, 0);
                }
            }
        }
        // invA reduce + x write (hi/lo into xcat, plain stores)
        rsA += __shfl_xor(rsA, 1, 64);
        rsA += __shfl_xor(rsA, 2, 64);
        if ((t & 3) == 0) invA[fhr] = 1.0f / (rsA + 1e-4f);
        __syncthreads();
        {
            float ia[4];
            #pragma unroll
            for (int r = 0; r < 4; ++r) ia[r] = invA[wv * 16 + kg * 4 + r];
            u16* xho = xcat_hi + (size_t)b * KTOT;
            u16* xlo = xcat_lo + (size_t)b * KTOT;
            #pragma unroll
            for (int ni = 0; ni < 4; ++ni) {
                const int col = ni * 16 + fr;
                #pragma unroll
                for (int r = 0; r < 4; ++r) {
                    float v = xacc[ni][r] * ia[r];
                    u16 hv = f2bf(v);
                    const int o = (wv * 16 + kg * 4 + r) * GSZ + col;
                    xho[o] = hv;
                    xlo[o] = f2bf(v - bf2f(hv));
                }
            }
        }

        // prefetch weight tiles only when wc is known-stable (after barrier 1)
        s16x8 gld[8];
        if (step > 0) {
            #pragma unroll
            for (int q = 4; q < 8; ++q) gld[q] = *(const s16x8*)(gsrc0[q]);
        }

        gridbar(bar, 2 * step + 1);

        // ================= G phase: gates GEMM (split-K) =================
        {
            const u16* srcs[8];
            #pragma unroll
            for (int q = 0; q < 8; ++q) srcs[q] = gsrc0[q];
            if (step == 0) {
                #pragma unroll
                for (int q = 4; q < 8; ++q) gld[q] = *(const s16x8*)(srcs[q]);
            }
            #pragma unroll
            for (int q = 0; q < 4; ++q) gld[q] = ld_l3_16(srcs[q]);   // xcat: L2-bypass

            f32x4 gacc[4][4];
            #pragma unroll
            for (int mi = 0; mi < 4; ++mi)
                #pragma unroll
                for (int ni = 0; ni < 4; ++ni) gacc[mi][ni] = (f32x4)(0.f);

            for (int ks = 0; ks < KSTEPS; ++ks) {
                __syncthreads();
                #pragma unroll
                for (int q = 0; q < 8; ++q) {
                    *(s16x8*)(gdst[q]) = gld[q];
                    srcs[q] += 32;
                }
                __syncthreads();
                if (ks + 1 < KSTEPS) {
                    #pragma unroll
                    for (int q = 0; q < 4; ++q) gld[q] = ld_l3_16(srcs[q]);       // xcat
                    #pragma unroll
                    for (int q = 4; q < 8; ++q) gld[q] = *(const s16x8*)(srcs[q]); // wc cached
                }
                s16x8 ah[4], al[4], bh[4], bl[4];
                #pragma unroll
                for (int mi = 0; mi < 4; ++mi) {
                    const int r = wmG * 64 + mi * 16 + fr;
                    ah[mi] = *(const s16x8*)&gsm[0][r][kg * 8];
                    al[mi] = *(const s16x8*)&gsm[1][r][kg * 8];
                }
                #pragma unroll
                for (int ni = 0; ni < 4; ++ni) {
                    const int r = wnG * 64 + ni * 16 + fr;
                    bh[ni] = *(const s16x8*)&gsm[2][r][kg * 8];
                    bl[ni] = *(const s16x8*)&gsm[3][r][kg * 8];
                }
                #pragma unroll
                for (int mi = 0; mi < 4; ++mi)
                    #pragma unroll
                    for (int ni = 0; ni < 4; ++ni) {
                        gacc[mi][ni] = __builtin_amdgcn_mfma_f32_16x16x32_bf16(ah[mi], bh[ni], gacc[mi][ni], 0, 0, 0);
                        gacc[mi][ni] = __builtin_amdgcn_mfma_f32_16x16x32_bf16(ah[mi], bl[ni], gacc[mi][ni], 0, 0, 0);
                        gacc[mi][ni] = __builtin_amdgcn_mfma_f32_16x16x32_bf16(al[mi], bh[ni], gacc[mi][ni], 0, 0, 0);
                    }
            }

            float* pp = part + ((size_t)kcG << 19);   // plain stores; flushed at next release
            #pragma unroll
            for (int mi = 0; mi < 4; ++mi) {
                const int mbase = m0G + wmG * 64 + mi * 16 + kg * 4;
                #pragma unroll
                for (int ni = 0; ni < 4; ++ni) {
                    const int col = n0G + wnG * 64 + ni * 16 + fr;
                    #pragma unroll
                    for (int r = 0; r < 4; ++r)
                        pp[(size_t)(mbase + r) * 2048 + col] = gacc[mi][ni][r];
                }
            }
        }
        gridbar(bar, 2 * step + 2);
    }

    // ================= final LSTM update -> out =================
    #pragma unroll
    for (int half = 0; half < 2; ++half) {
        const int u = t + half * 256;
        float gi = b_ih[u] + b_hh[u];
        float gf = b_ih[HID + u] + b_hh[HID + u];
        float gg = b_ih[2 * HID + u] + b_hh[2 * HID + u];
        float go = b_ih[3 * HID + u] + b_hh[3 * HID + u];
        const float* pb = part + (size_t)b * 2048;
        #pragma unroll
        for (int kc = 0; kc < SPLITK; ++kc) {
            const float* p = pb + (size_t)kc * (256 * 2048);
            gi += ld_l3_f32(p + u);
            gf += ld_l3_f32(p + HID + u);
            gg += ld_l3_f32(p + 2 * HID + u);
            go += ld_l3_f32(p + 3 * HID + u);
        }
        float co = half ? cx1 : cx0;
        float c = sigm(gf) * co + sigm(gi) * tanhf(gg);
        float h = sigm(go) * tanhf(c);
        out[(size_t)b * HID + u] = h;
    }
}

extern "C" void kernel_launch(void* const* d_in, const int* in_sizes, int n_in,
                              void* d_out, int out_size, void* d_ws, size_t ws_size,
                              hipStream_t stream) {
    const float* imgs = (const float*)d_in[0];
    const float* W_ih = (const float*)d_in[1];
    const float* W_hh = (const float*)d_in[2];
    const float* b_ih = (const float*)d_in[3];
    const float* b_hh = (const float*)d_in[4];
    const float* W_g  = (const float*)d_in[5];
    const float* b_g  = (const float*)d_in[6];
    float* out = (float*)d_out;

    char* w = (char*)d_ws;
    int* bar       = (int*)w;    w += 4096;                     // 257 ints used
    u16* xcat_hi   = (u16*)w;    w += (size_t)NB * KTOT * 2;
    u16* xcat_lo   = (u16*)w;    w += (size_t)NB * KTOT * 2;
    u16* wc_hi     = (u16*)w;    w += (size_t)2048 * KTOT * 2;
    u16* wc_lo     = (u16*)w;    w += (size_t)2048 * KTOT * 2;
    float* part    = (float*)w;  w += (size_t)SPLITK * NB * 2048 * 4;

    // barrier state must start at 0 every call (ws is poisoned once, not re-poisoned)
    hipMemsetAsync(bar, 0, 4096, stream);

    k_all<<<NB, 256, 0, stream>>>(imgs, W_ih, W_hh, b_ih, b_hh, W_g, b_g,
                                  bar, wc_hi, wc_lo, xcat_hi, xcat_lo, part, out);
}

// Round 10
// 1710.103 us; speedup vs baseline: 1.1057x; 1.1057x over previous
//
#include <hip/hip_runtime.h>
#include <math.h>

#define NB 256
#define IMG 256
#define GSZ 64
#define HID 512
#define NSTEP 16
#define KTOT 4608            // 4096 (x) + 512 (Hx)
#define SPLITK 8
#define KCHUNK 576           // KTOT / SPLITK
#define KSTEPS 18            // KCHUNK / 32
#define SP 40                // img-stage / Fw-chunk pitch (u16)
#define TP 72                // t1T / Fh chunk pitch (u16)

typedef unsigned short u16;
typedef unsigned int u32;
typedef unsigned long long u64;
typedef __attribute__((ext_vector_type(8))) short s16x8;   // 8 bf16
typedef __attribute__((ext_vector_type(4))) float f32x4;

__device__ inline u16 f2bf(float f) {           // round-to-nearest-even bf16
    unsigned u = __float_as_uint(f);
    unsigned r = u + 0x7fffu + ((u >> 16) & 1u);
    return (u16)(r >> 16);
}
__device__ inline float bf2f(u16 h) { return __uint_as_float((unsigned)h << 16); }
__device__ inline float sigm(float v) { return 1.0f / (1.0f + expf(-v)); }

// ---- L3-direct (agent-scope, L2-bypass) accessors for cross-block data ----
__device__ inline s16x8 ld_l3_16(const u16* p) {
    union { s16x8 v; u64 q[2]; } u;
    u.q[0] = __hip_atomic_load((const u64*)p,       __ATOMIC_RELAXED, __HIP_MEMORY_SCOPE_AGENT);
    u.q[1] = __hip_atomic_load((const u64*)(p + 4), __ATOMIC_RELAXED, __HIP_MEMORY_SCOPE_AGENT);
    return u.v;
}
__device__ inline float2 ld_l3_f32x2(const float* p) {   // p 8B-aligned
    u64 q = __hip_atomic_load((const u64*)p, __ATOMIC_RELAXED, __HIP_MEMORY_SCOPE_AGENT);
    union { u64 q; float2 f; } u; u.q = q; return u.f;
}
__device__ inline void st_l3_u32(u16* p, u32 v) {        // p 4B-aligned
    __hip_atomic_store((u32*)p, v, __ATOMIC_RELAXED, __HIP_MEMORY_SCOPE_AGENT);
}
__device__ inline void st_l3_u64(u16* p, u64 v) {        // p 8B-aligned
    __hip_atomic_store((u64*)p, v, __ATOMIC_RELAXED, __HIP_MEMORY_SCOPE_AGENT);
}
__device__ inline void st_l3_f32(float* p, float v) {
    __hip_atomic_store(p, v, __ATOMIC_RELAXED, __HIP_MEMORY_SCOPE_AGENT);
}

// software grid barrier with ZERO cache-maintenance ops.
// All cross-block data moves via sc1 (L3-direct) atomics, so no wbl2/inv is
// needed (r8/r9's release stores each triggered a full-L2 buffer_wbl2 -> ~50us
// per barrier). Ordering: every wave drains its own vmem (sc1 stores reach L3),
// __syncthreads, then a RELAXED flag store; consumers observe flag in L3 and
// read data from L3.
__device__ inline void gridbar(int* bar, int gen) {
    asm volatile("s_waitcnt vmcnt(0) lgkmcnt(0)" ::: "memory");  // per-wave drain
    __syncthreads();
    const int b = blockIdx.x, t = threadIdx.x;
    if (b == 0) {
        if (t > 0) {          // thread t watches block t's arrive flag
            while (__hip_atomic_load(&bar[1 + t], __ATOMIC_RELAXED,
                                     __HIP_MEMORY_SCOPE_AGENT) < gen)
                __builtin_amdgcn_s_sleep(4);
        }
        __syncthreads();      // all arrivals observed (their data already in L3)
        if (t == 0)
            __hip_atomic_store(&bar[0], gen, __ATOMIC_RELAXED,
                               __HIP_MEMORY_SCOPE_AGENT);
    } else {
        if (t == 0) {
            __hip_atomic_store(&bar[1 + b], gen, __ATOMIC_RELAXED,
                               __HIP_MEMORY_SCOPE_AGENT);
            while (__hip_atomic_load(&bar[0], __ATOMIC_RELAXED,
                                     __HIP_MEMORY_SCOPE_AGENT) < gen)
                __builtin_amdgcn_s_sleep(4);
        }
        __syncthreads();
    }
    asm volatile("" ::: "memory");   // compiler barrier: no motion across the spin
}

__global__ __launch_bounds__(256, 2) void k_all(
    const float* __restrict__ imgs, const float* __restrict__ W_ih,
    const float* __restrict__ W_hh, const float* __restrict__ b_ih,
    const float* __restrict__ b_hh, const float* __restrict__ W_g,
    const float* __restrict__ b_g,
    int* __restrict__ bar,
    u16* __restrict__ wc_hi, u16* __restrict__ wc_lo,
    u16* __restrict__ xcat_hi, u16* __restrict__ xcat_lo,
    float* __restrict__ part, float* __restrict__ out)
{
    // 51,200 B overlaid static LDS (+ small scratch) -- fits default 64 KB
    __shared__ __align__(16) u16 sm[25600];
    __shared__ float invW[64];
    __shared__ float invA[64];
    __shared__ float red[12];
    // phase-1 overlay
    u16* AstH = sm;            // [256][SP] img chunk hi
    u16* AstL = sm + 10240;    // [256][SP] img chunk lo
    u16* FwcH = sm + 20480;    // [64][SP]  Fw chunk hi
    u16* FwcL = sm + 23040;    // [64][SP]  Fw chunk lo
    // phase-2 overlay
    u16* t1TH = sm;            // [64][TP]  t1T chunk hi
    u16* t1TL = sm + 4608;
    u16* FhcH = sm + 9216;     // [64][TP]  Fh chunk hi
    u16* FhcL = sm + 13824;
    float* xs = (float*)sm;    // [64][66] f32 x-tile staging (post phase-2)
    // G-phase overlay
    u16 (*gsm)[128][40] = (u16 (*)[128][40])sm;

    const int b = blockIdx.x, t = threadIdx.x;
    const int lane = t & 63, wv = t >> 6;
    const int fr = lane & 15, kg = lane >> 4;

    // persistent LSTM state: units 2t and 2t+1 of batch b
    float hx0 = 0.f, hx1 = 0.f, cx0 = 0.f, cx1 = 0.f;

    // G-phase tiling (constant per block)
    const int mbG = b & 1;
    const int nbG = (b >> 1) & 15;
    const int kcG = b >> 5;
    const int m0G = mbG * 128, n0G = nbG * 128, k0G = kcG * KCHUNK;
    const int wmG = wv >> 1, wnG = wv & 1;
    const u16* gsrc0[8];       // start-of-chunk source pointers
    u16* gdst[8];
    #pragma unroll
    for (int q = 0; q < 8; ++q) {
        const int idx = ((q * 256 + t) & 511);
        const int row = idx >> 2;
        const int ko = (idx & 3) * 8;
        const int mat = q >> 1;
        const u16* gbase;
        if (mat == 0)      gbase = xcat_hi + (size_t)(m0G + row) * KTOT;
        else if (mat == 1) gbase = xcat_lo + (size_t)(m0G + row) * KTOT;
        else if (mat == 2) gbase = wc_hi + (size_t)(n0G + row) * KTOT;
        else               gbase = wc_lo + (size_t)(n0G + row) * KTOT;
        gsrc0[q] = gbase + k0G + ko;
        gdst[q] = &gsm[mat][row][ko];
    }

    // ---------- weight split phase (wc = [W_ih | W_hh] hi/lo, L3-direct) ----------
    {
        const int nchunk = 2048 * KTOT / 4;      // 2,359,296
        for (int c = b * 256 + t; c < nchunk; c += 65536) {
            const int j = c / (KTOT / 4);
            const int k = (c - j * (KTOT / 4)) * 4;
            float4 v;
            if (k < 4096) v = *(const float4*)&W_ih[(size_t)j * 4096 + k];
            else          v = *(const float4*)&W_hh[(size_t)j * 512 + (k - 4096)];
            float f[4] = {v.x, v.y, v.z, v.w};
            u64 hq = 0, lq = 0;
            #pragma unroll
            for (int i = 0; i < 4; ++i) {
                u16 hi = f2bf(f[i]);
                u16 lo = f2bf(f[i] - bf2f(hi));
                hq |= (u64)hi << (16 * i);
                lq |= (u64)lo << (16 * i);
            }
            const size_t o = (size_t)j * KTOT + k;
            st_l3_u64(&wc_hi[o], hq);
            st_l3_u64(&wc_lo[o], lq);
        }
    }
    // first wc read is in G(0), after the first grid barrier (race-free)

    for (int step = 0; step < NSTEP; ++step) {
        // ========== LSTM update from previous step's partials ==========
        if (step == 0) {
            const size_t o = (size_t)b * KTOT + 4096 + 2 * t;
            st_l3_u32(&xcat_hi[o], 0u);
            st_l3_u32(&xcat_lo[o], 0u);
        } else {
            const int u0 = 2 * t, u1 = 2 * t + 1;
            float gi0 = b_ih[u0] + b_hh[u0],             gi1 = b_ih[u1] + b_hh[u1];
            float gf0 = b_ih[HID + u0] + b_hh[HID + u0], gf1 = b_ih[HID + u1] + b_hh[HID + u1];
            float gg0 = b_ih[2*HID + u0] + b_hh[2*HID + u0], gg1 = b_ih[2*HID + u1] + b_hh[2*HID + u1];
            float go0 = b_ih[3*HID + u0] + b_hh[3*HID + u0], go1 = b_ih[3*HID + u1] + b_hh[3*HID + u1];
            const float* pb = part + (size_t)b * 2048;
            #pragma unroll
            for (int kc = 0; kc < SPLITK; ++kc) {
                const float* p = pb + (size_t)kc * (256 * 2048);
                float2 a = ld_l3_f32x2(p + u0);
                float2 c = ld_l3_f32x2(p + HID + u0);
                float2 d = ld_l3_f32x2(p + 2 * HID + u0);
                float2 e = ld_l3_f32x2(p + 3 * HID + u0);
                gi0 += a.x; gi1 += a.y;
                gf0 += c.x; gf1 += c.y;
                gg0 += d.x; gg1 += d.y;
                go0 += e.x; go1 += e.y;
            }
            float c0 = sigm(gf0) * cx0 + sigm(gi0) * tanhf(gg0);
            float c1 = sigm(gf1) * cx1 + sigm(gi1) * tanhf(gg1);
            float h0 = sigm(go0) * tanhf(c0);
            float h1 = sigm(go1) * tanhf(c1);
            cx0 = c0; cx1 = c1; hx0 = h0; hx1 = h1;
            u16 hh0 = f2bf(h0), hh1 = f2bf(h1);
            u16 hl0 = f2bf(h0 - bf2f(hh0)), hl1 = f2bf(h1 - bf2f(hh1));
            const size_t o = (size_t)b * KTOT + 4096 + 2 * t;
            st_l3_u32(&xcat_hi[o], (u32)hh0 | ((u32)hh1 << 16));
            st_l3_u32(&xcat_lo[o], (u32)hl0 | ((u32)hl1 << 16));
        }
        // ========== params: gp = tanh(Hx @ W_g^T + b_g) ==========
        float2 wg0 = *(const float2*)&W_g[2 * t];
        float2 wg1 = *(const float2*)&W_g[HID + 2 * t];
        float2 wg2 = *(const float2*)&W_g[2 * HID + 2 * t];
        float s0 = hx0 * wg0.x + hx1 * wg0.y;
        float s1 = hx0 * wg1.x + hx1 * wg1.y;
        float s2 = hx0 * wg2.x + hx1 * wg2.y;
        for (int off = 32; off; off >>= 1) {
            s0 += __shfl_xor(s0, off, 64);
            s1 += __shfl_xor(s1, off, 64);
            s2 += __shfl_xor(s2, off, 64);
        }
        __syncthreads();
        if (lane == 0) { red[wv * 3 + 0] = s0; red[wv * 3 + 1] = s1; red[wv * 3 + 2] = s2; }
        __syncthreads();
        s0 = red[0] + red[3] + red[6] + red[9];
        s1 = red[1] + red[4] + red[7] + red[10];
        s2 = red[2] + red[5] + red[8] + red[11];
        const float g0 = tanhf(s0 + b_g[0]);
        const float g1 = tanhf(s1 + b_g[1]);
        const float g2 = tanhf(s2 + b_g[2]);
        const float ad = fabsf(g2);
        const float ch = 127.5f * (g0 + 1.0f);
        const float cw = 127.5f * (g1 + 1.0f);
        const float dl = 4.0f * (1.0f - ad);
        const float gm = expf(1.0f - 2.0f * ad);
        const float ig = 1.0f / gm;
        const float coef = 1.0f / (3.14159265358979323846f * gm);

        // ========== glimpse phase 1: t1T[gw][h] = sum_w Fw[gw][w]*img[h][w] ==========
        const int fwr = t >> 2;              // gw row this thread fills
        const int fwc = (t & 3) * 8;         // col offset within 32-chunk
        const float rcw = cw + dl * ((float)fwr - 31.5f);
        float rsW = 0.f;

        const float* imgp = imgs + (size_t)(b * 2 + (step & 1)) * (IMG * IMG);
        int rowA[8], coA[8];
        float4 pf[8];
        #pragma unroll
        for (int q = 0; q < 8; ++q) {
            const int c = q * 256 + t;
            rowA[q] = c >> 3;
            coA[q]  = (c & 7) * 4;
            pf[q] = *(const float4*)&imgp[rowA[q] * IMG + coA[q]];
        }
        f32x4 acc[4][4];
        #pragma unroll
        for (int mi = 0; mi < 4; ++mi)
            #pragma unroll
            for (int ni = 0; ni < 4; ++ni) acc[mi][ni] = (f32x4)(0.f);

        for (int ks = 0; ks < 8; ++ks) {
            __syncthreads();
            #pragma unroll
            for (int q = 0; q < 8; ++q) {
                float f[4] = {pf[q].x, pf[q].y, pf[q].z, pf[q].w};
                u16 hh[4], ll[4];
                #pragma unroll
                for (int j = 0; j < 4; ++j) {
                    hh[j] = f2bf(f[j]);
                    ll[j] = f2bf(f[j] - bf2f(hh[j]));
                }
                *(ushort4*)&AstH[rowA[q] * SP + coA[q]] = make_ushort4(hh[0], hh[1], hh[2], hh[3]);
                *(ushort4*)&AstL[rowA[q] * SP + coA[q]] = make_ushort4(ll[0], ll[1], ll[2], ll[3]);
            }
            {
                u16 hh[8], ll[8];
                #pragma unroll
                for (int j = 0; j < 8; ++j) {
                    float u = ((float)(ks * 32 + fwc + j) - rcw) * ig;
                    float val = coef / (1.0f + u * u);
                    rsW += val;
                    hh[j] = f2bf(val);
                    ll[j] = f2bf(val - bf2f(hh[j]));
                }
                *(ushort4*)&FwcH[fwr * SP + fwc]     = make_ushort4(hh[0], hh[1], hh[2], hh[3]);
                *(ushort4*)&FwcH[fwr * SP + fwc + 4] = make_ushort4(hh[4], hh[5], hh[6], hh[7]);
                *(ushort4*)&FwcL[fwr * SP + fwc]     = make_ushort4(ll[0], ll[1], ll[2], ll[3]);
                *(ushort4*)&FwcL[fwr * SP + fwc + 4] = make_ushort4(ll[4], ll[5], ll[6], ll[7]);
            }
            __syncthreads();
            if (ks < 7) {
                #pragma unroll
                for (int q = 0; q < 8; ++q)
                    pf[q] = *(const float4*)&imgp[rowA[q] * IMG + (ks + 1) * 32 + coA[q]];
            }
            s16x8 ah[4], al[4], bh[4], bl[4];
            #pragma unroll
            for (int mi = 0; mi < 4; ++mi) {
                const int r = mi * 16 + fr;
                ah[mi] = *(const s16x8*)&FwcH[r * SP + kg * 8];
                al[mi] = *(const s16x8*)&FwcL[r * SP + kg * 8];
            }
            #pragma unroll
            for (int ni = 0; ni < 4; ++ni) {
                const int r = wv * 64 + ni * 16 + fr;
                bh[ni] = *(const s16x8*)&AstH[r * SP + kg * 8];
                bl[ni] = *(const s16x8*)&AstL[r * SP + kg * 8];
            }
            #pragma unroll
            for (int mi = 0; mi < 4; ++mi)
                #pragma unroll
                for (int ni = 0; ni < 4; ++ni) {
                    acc[mi][ni] = __builtin_amdgcn_mfma_f32_16x16x32_bf16(ah[mi], bh[ni], acc[mi][ni], 0, 0, 0);
                    acc[mi][ni] = __builtin_amdgcn_mfma_f32_16x16x32_bf16(ah[mi], bl[ni], acc[mi][ni], 0, 0, 0);
                    acc[mi][ni] = __builtin_amdgcn_mfma_f32_16x16x32_bf16(al[mi], bh[ni], acc[mi][ni], 0, 0, 0);
                }
        }
        // invW reduce (4 consecutive lanes per row) and scale accumulators
        rsW += __shfl_xor(rsW, 1, 64);
        rsW += __shfl_xor(rsW, 2, 64);
        if ((t & 3) == 0) invW[fwr] = 1.0f / (rsW + 1e-4f);
        __syncthreads();
        #pragma unroll
        for (int mi = 0; mi < 4; ++mi) {
            float w4[4];
            #pragma unroll
            for (int r = 0; r < 4; ++r) w4[r] = invW[mi * 16 + kg * 4 + r];
            #pragma unroll
            for (int ni = 0; ni < 4; ++ni)
                #pragma unroll
                for (int r = 0; r < 4; ++r) acc[mi][ni][r] *= w4[r];
        }

        // ========== glimpse phase 2: x[gh][gw] = invA[gh]*sum_h Fh[gh][h]*t1T[gw][h] ==========
        f32x4 xacc[4];
        #pragma unroll
        for (int ni = 0; ni < 4; ++ni) xacc[ni] = (f32x4)(0.f);
        const int fhr = t >> 2;              // gh row this thread fills
        const int fhc = (t & 3) * 16;        // col offset within 64-chunk
        const float rch = ch + dl * ((float)fhr - 31.5f);
        float rsA = 0.f;

        for (int p = 0; p < 4; ++p) {
            __syncthreads();
            #pragma unroll
            for (int blk = 0; blk < 4; ++blk) {
                u16 hh[4], ll[4];
                #pragma unroll
                for (int j = 0; j < 4; ++j) {
                    float u = ((float)(p * 64 + fhc + blk * 4 + j) - rch) * ig;
                    float val = coef / (1.0f + u * u);
                    rsA += val;
                    hh[j] = f2bf(val);
                    ll[j] = f2bf(val - bf2f(hh[j]));
                }
                *(ushort4*)&FhcH[fhr * TP + fhc + blk * 4] = make_ushort4(hh[0], hh[1], hh[2], hh[3]);
                *(ushort4*)&FhcL[fhr * TP + fhc + blk * 4] = make_ushort4(ll[0], ll[1], ll[2], ll[3]);
            }
            if (wv == p) {
                #pragma unroll
                for (int mi = 0; mi < 4; ++mi)
                    #pragma unroll
                    for (int ni = 0; ni < 4; ++ni)
                        #pragma unroll
                        for (int r = 0; r < 4; ++r) {
                            const int row = mi * 16 + kg * 4 + r;   // gw
                            const int col = ni * 16 + fr;           // local h
                            float v = acc[mi][ni][r];
                            u16 hv = f2bf(v);
                            t1TH[row * TP + col] = hv;
                            t1TL[row * TP + col] = f2bf(v - bf2f(hv));
                        }
            }
            __syncthreads();
            #pragma unroll
            for (int k2 = 0; k2 < 2; ++k2) {
                const int ra = wv * 16 + fr;
                s16x8 a2h = *(const s16x8*)&FhcH[ra * TP + k2 * 32 + kg * 8];
                s16x8 a2l = *(const s16x8*)&FhcL[ra * TP + k2 * 32 + kg * 8];
                #pragma unroll
                for (int ni = 0; ni < 4; ++ni) {
                    const int rb = ni * 16 + fr;
                    s16x8 b2h = *(const s16x8*)&t1TH[rb * TP + k2 * 32 + kg * 8];
                    s16x8 b2l = *(const s16x8*)&t1TL[rb * TP + k2 * 32 + kg * 8];
                    xacc[ni] = __builtin_amdgcn_mfma_f32_16x16x32_bf16(a2h, b2h, xacc[ni], 0, 0, 0);
                    xacc[ni] = __builtin_amdgcn_mfma_f32_16x16x32_bf16(a2h, b2l, xacc[ni], 0, 0, 0);
                    xacc[ni] = __builtin_amdgcn_mfma_f32_16x16x32_bf16(a2l, b2h, xacc[ni], 0, 0, 0);
                }
            }
        }
        // invA reduce; stage x tile to LDS as f32; pack & store L3-direct
        rsA += __shfl_xor(rsA, 1, 64);
        rsA += __shfl_xor(rsA, 2, 64);
        if ((t & 3) == 0) invA[fhr] = 1.0f / (rsA + 1e-4f);
        __syncthreads();   // also: all phase-2 LDS reads done -> xs overlay safe
        {
            float ia[4];
            #pragma unroll
            for (int r = 0; r < 4; ++r) ia[r] = invA[wv * 16 + kg * 4 + r];
            #pragma unroll
            for (int ni = 0; ni < 4; ++ni) {
                const int col = ni * 16 + fr;
                #pragma unroll
                for (int r = 0; r < 4; ++r)
                    xs[(wv * 16 + kg * 4 + r) * 66 + col] = xacc[ni][r] * ia[r];
            }
        }
        __syncthreads();
        {
            u16* xho = xcat_hi + (size_t)b * KTOT;
            u16* xlo = xcat_lo + (size_t)b * KTOT;
            #pragma unroll
            for (int pi = 0; pi < 8; ++pi) {
                const int idx = t * 8 + pi;          // u32-pair index in 64x64 tile
                const int row = idx >> 5;
                const int c2 = (idx & 31) * 2;
                float v0 = xs[row * 66 + c2];
                float v1 = xs[row * 66 + c2 + 1];
                u16 h0 = f2bf(v0), h1 = f2bf(v1);
                u16 l0 = f2bf(v0 - bf2f(h0)), l1 = f2bf(v1 - bf2f(h1));
                st_l3_u32(&xho[row * GSZ + c2], (u32)h0 | ((u32)h1 << 16));
                st_l3_u32(&xlo[row * GSZ + c2], (u32)l0 | ((u32)l1 << 16));
            }
        }

        // prefetch weight tiles only when wc is known-stable (after barrier 1)
        s16x8 gld[8];
        if (step > 0) {
            #pragma unroll
            for (int q = 4; q < 8; ++q) gld[q] = *(const s16x8*)(gsrc0[q]);
        }

        gridbar(bar, 2 * step + 1);

        // ================= G phase: gates GEMM (split-K) =================
        {
            const u16* srcs[8];
            #pragma unroll
            for (int q = 0; q < 8; ++q) srcs[q] = gsrc0[q];
            if (step == 0) {
                #pragma unroll
                for (int q = 4; q < 8; ++q) gld[q] = ld_l3_16(srcs[q]);  // wc via L3 (step 0)
            }
            #pragma unroll
            for (int q = 0; q < 4; ++q) gld[q] = ld_l3_16(srcs[q]);   // xcat: L3-direct

            f32x4 gacc[4][4];
            #pragma unroll
            for (int mi = 0; mi < 4; ++mi)
                #pragma unroll
                for (int ni = 0; ni < 4; ++ni) gacc[mi][ni] = (f32x4)(0.f);

            for (int ks = 0; ks < KSTEPS; ++ks) {
                __syncthreads();
                #pragma unroll
                for (int q = 0; q < 8; ++q) {
                    *(s16x8*)(gdst[q]) = gld[q];
                    srcs[q] += 32;
                }
                __syncthreads();
                if (ks + 1 < KSTEPS) {
                    #pragma unroll
                    for (int q = 0; q < 4; ++q) gld[q] = ld_l3_16(srcs[q]);       // xcat
                    #pragma unroll
                    for (int q = 4; q < 8; ++q) gld[q] = *(const s16x8*)(srcs[q]); // wc cached (immutable)
                }
                s16x8 ah[4], al[4], bh[4], bl[4];
                #pragma unroll
                for (int mi = 0; mi < 4; ++mi) {
                    const int r = wmG * 64 + mi * 16 + fr;
                    ah[mi] = *(const s16x8*)&gsm[0][r][kg * 8];
                    al[mi] = *(const s16x8*)&gsm[1][r][kg * 8];
                }
                #pragma unroll
                for (int ni = 0; ni < 4; ++ni) {
                    const int r = wnG * 64 + ni * 16 + fr;
                    bh[ni] = *(const s16x8*)&gsm[2][r][kg * 8];
                    bl[ni] = *(const s16x8*)&gsm[3][r][kg * 8];
                }
                #pragma unroll
                for (int mi = 0; mi < 4; ++mi)
                    #pragma unroll
                    for (int ni = 0; ni < 4; ++ni) {
                        gacc[mi][ni] = __builtin_amdgcn_mfma_f32_16x16x32_bf16(ah[mi], bh[ni], gacc[mi][ni], 0, 0, 0);
                        gacc[mi][ni] = __builtin_amdgcn_mfma_f32_16x16x32_bf16(ah[mi], bl[ni], gacc[mi][ni], 0, 0, 0);
                        gacc[mi][ni] = __builtin_amdgcn_mfma_f32_16x16x32_bf16(al[mi], bh[ni], gacc[mi][ni], 0, 0, 0);
                    }
            }

            float* pp = part + ((size_t)kcG << 19);   // L3-direct stores
            #pragma unroll
            for (int mi = 0; mi < 4; ++mi) {
                const int mbase = m0G + wmG * 64 + mi * 16 + kg * 4;
                #pragma unroll
                for (int ni = 0; ni < 4; ++ni) {
                    const int col = n0G + wnG * 64 + ni * 16 + fr;
                    #pragma unroll
                    for (int r = 0; r < 4; ++r)
                        st_l3_f32(&pp[(size_t)(mbase + r) * 2048 + col], gacc[mi][ni][r]);
                }
            }
        }
        gridbar(bar, 2 * step + 2);
    }

    // ================= final LSTM update -> out =================
    {
        const int u0 = 2 * t, u1 = 2 * t + 1;
        float gi0 = b_ih[u0] + b_hh[u0],             gi1 = b_ih[u1] + b_hh[u1];
        float gf0 = b_ih[HID + u0] + b_hh[HID + u0], gf1 = b_ih[HID + u1] + b_hh[HID + u1];
        float gg0 = b_ih[2*HID + u0] + b_hh[2*HID + u0], gg1 = b_ih[2*HID + u1] + b_hh[2*HID + u1];
        float go0 = b_ih[3*HID + u0] + b_hh[3*HID + u0], go1 = b_ih[3*HID + u1] + b_hh[3*HID + u1];
        const float* pb = part + (size_t)b * 2048;
        #pragma unroll
        for (int kc = 0; kc < SPLITK; ++kc) {
            const float* p = pb + (size_t)kc * (256 * 2048);
            float2 a = ld_l3_f32x2(p + u0);
            float2 c = ld_l3_f32x2(p + HID + u0);
            float2 d = ld_l3_f32x2(p + 2 * HID + u0);
            float2 e = ld_l3_f32x2(p + 3 * HID + u0);
            gi0 += a.x; gi1 += a.y;
            gf0 += c.x; gf1 += c.y;
            gg0 += d.x; gg1 += d.y;
            go0 += e.x; go1 += e.y;
        }
        float c0 = sigm(gf0) * cx0 + sigm(gi0) * tanhf(gg0);
        float c1 = sigm(gf1) * cx1 + sigm(gi1) * tanhf(gg1);
        float h0 = sigm(go0) * tanhf(c0);
        float h1 = sigm(go1) * tanhf(c1);
        out[(size_t)b * HID + u0] = h0;
        out[(size_t)b * HID + u1] = h1;
    }
}

extern "C" void kernel_launch(void* const* d_in, const int* in_sizes, int n_in,
                              void* d_out, int out_size, void* d_ws, size_t ws_size,
                              hipStream_t stream) {
    const float* imgs = (const float*)d_in[0];
    const float* W_ih = (const float*)d_in[1];
    const float* W_hh = (const float*)d_in[2];
    const float* b_ih = (const float*)d_in[3];
    const float* b_hh = (const float*)d_in[4];
    const float* W_g  = (const float*)d_in[5];
    const float* b_g  = (const float*)d_in[6];
    float* out = (float*)d_out;

    char* w = (char*)d_ws;
    int* bar       = (int*)w;    w += 4096;                     // 257 ints used
    u16* xcat_hi   = (u16*)w;    w += (size_t)NB * KTOT * 2;
    u16* xcat_lo   = (u16*)w;    w += (size_t)NB * KTOT * 2;
    u16* wc_hi     = (u16*)w;    w += (size_t)2048 * KTOT * 2;
    u16* wc_lo     = (u16*)w;    w += (size_t)2048 * KTOT * 2;
    float* part    = (float*)w;  w += (size_t)SPLITK * NB * 2048 * 4;

    // barrier state must start at 0 every call (ws is poisoned once, not re-poisoned)
    hipMemsetAsync(bar, 0, 4096, stream);

    k_all<<<NB, 256, 0, stream>>>(imgs, W_ih, W_hh, b_ih, b_hh, W_g, b_g,
                                  bar, wc_hi, wc_lo, xcat_hi, xcat_lo, part, out);
}

// Round 11
// 1567.226 us; speedup vs baseline: 1.2065x; 1.0912x over previous
//
#include <hip/hip_runtime.h>
#include <math.h>

#define NB 256
#define IMG 256
#define GSZ 64
#define HID 512
#define NSTEP 16
#define KTOT 4608            // 4096 (x) + 512 (Hx)
#define SPLITK 8
#define KCHUNK 576           // KTOT / SPLITK
#define KSTEPS 18            // KCHUNK / 32
#define SP 40                // img-stage / Fw-chunk pitch (u16)
#define TP 72                // t1T / Fh chunk pitch (u16)

typedef unsigned short u16;
typedef unsigned int u32;
typedef unsigned long long u64;
typedef __attribute__((ext_vector_type(8))) short s16x8;   // 8 bf16
typedef __attribute__((ext_vector_type(4))) float f32x4;

__device__ inline u16 f2bf(float f) {           // round-to-nearest-even bf16
    unsigned u = __float_as_uint(f);
    unsigned r = u + 0x7fffu + ((u >> 16) & 1u);
    return (u16)(r >> 16);
}
__device__ inline float bf2f(u16 h) { return __uint_as_float((unsigned)h << 16); }
__device__ inline float sigm(float v) { return 1.0f / (1.0f + expf(-v)); }

// ---- L3-direct (agent-scope, L2-bypass) accessors for cross-block data ----
__device__ inline s16x8 ld_l3_16(const u16* p) {
    union { s16x8 v; u64 q[2]; } u;
    u.q[0] = __hip_atomic_load((const u64*)p,       __ATOMIC_RELAXED, __HIP_MEMORY_SCOPE_AGENT);
    u.q[1] = __hip_atomic_load((const u64*)(p + 4), __ATOMIC_RELAXED, __HIP_MEMORY_SCOPE_AGENT);
    return u.v;
}
__device__ inline float2 ld_l3_f32x2(const float* p) {   // p 8B-aligned
    u64 q = __hip_atomic_load((const u64*)p, __ATOMIC_RELAXED, __HIP_MEMORY_SCOPE_AGENT);
    union { u64 q; float2 f; } u; u.q = q; return u.f;
}
__device__ inline void st_l3_u32(u16* p, u32 v) {        // p 4B-aligned
    __hip_atomic_store((u32*)p, v, __ATOMIC_RELAXED, __HIP_MEMORY_SCOPE_AGENT);
}
__device__ inline void st_l3_u64(u16* p, u64 v) {        // p 8B-aligned
    __hip_atomic_store((u64*)p, v, __ATOMIC_RELAXED, __HIP_MEMORY_SCOPE_AGENT);
}
__device__ inline void st_l3_f32(float* p, float v) {
    __hip_atomic_store(p, v, __ATOMIC_RELAXED, __HIP_MEMORY_SCOPE_AGENT);
}
// nontemporal image load: read-once data must not evict L2-pinned weights
__device__ inline float4 ld_nt_f32x4(const float* p) {
    f32x4 v = __builtin_nontemporal_load((const f32x4*)p);
    return make_float4(v[0], v[1], v[2], v[3]);
}

// software grid barrier with ZERO cache-maintenance ops (see r10 notes).
__device__ inline void gridbar(int* bar, int gen) {
    asm volatile("s_waitcnt vmcnt(0) lgkmcnt(0)" ::: "memory");  // per-wave drain
    __syncthreads();
    const int b = blockIdx.x, t = threadIdx.x;
    if (b == 0) {
        if (t > 0) {          // thread t watches block t's arrive flag
            while (__hip_atomic_load(&bar[1 + t], __ATOMIC_RELAXED,
                                     __HIP_MEMORY_SCOPE_AGENT) < gen)
                __builtin_amdgcn_s_sleep(4);
        }
        __syncthreads();      // all arrivals observed (their data already in L3)
        if (t == 0)
            __hip_atomic_store(&bar[0], gen, __ATOMIC_RELAXED,
                               __HIP_MEMORY_SCOPE_AGENT);
    } else {
        if (t == 0) {
            __hip_atomic_store(&bar[1 + b], gen, __ATOMIC_RELAXED,
                               __HIP_MEMORY_SCOPE_AGENT);
            while (__hip_atomic_load(&bar[0], __ATOMIC_RELAXED,
                                     __HIP_MEMORY_SCOPE_AGENT) < gen)
                __builtin_amdgcn_s_sleep(4);
        }
        __syncthreads();
    }
    asm volatile("" ::: "memory");   // compiler barrier: no motion across the spin
}

__global__ __launch_bounds__(256, 2) void k_all(
    const float* __restrict__ imgs, const float* __restrict__ W_ih,
    const float* __restrict__ W_hh, const float* __restrict__ b_ih,
    const float* __restrict__ b_hh, const float* __restrict__ W_g,
    const float* __restrict__ b_g,
    int* __restrict__ bar,
    u16* __restrict__ wc_hi, u16* __restrict__ wc_lo,
    u16* __restrict__ xcat_hi, u16* __restrict__ xcat_lo,
    float* __restrict__ part, float* __restrict__ out)
{
    // 51,200 B overlaid static LDS (+ small scratch) -- fits default 64 KB
    __shared__ __align__(16) u16 sm[25600];
    __shared__ float invW[64];
    __shared__ float invA[64];
    __shared__ float red[12];
    // phase-1 overlay
    u16* AstH = sm;            // [256][SP] img chunk hi
    u16* AstL = sm + 10240;    // [256][SP] img chunk lo
    u16* FwcH = sm + 20480;    // [64][SP]  Fw chunk hi
    u16* FwcL = sm + 23040;    // [64][SP]  Fw chunk lo
    // phase-2 overlay
    u16* t1TH = sm;            // [64][TP]  t1T chunk hi
    u16* t1TL = sm + 4608;
    u16* FhcH = sm + 9216;     // [64][TP]  Fh chunk hi
    u16* FhcL = sm + 13824;
    float* xs = (float*)sm;    // [64][66] f32 x-tile staging (post phase-2)
    // G-phase overlay
    u16 (*gsm)[128][40] = (u16 (*)[128][40])sm;

    const int b = blockIdx.x, t = threadIdx.x;
    const int lane = t & 63, wv = t >> 6;
    const int fr = lane & 15, kg = lane >> 4;

    // persistent LSTM state: units 2t and 2t+1 of batch b
    float hx0 = 0.f, hx1 = 0.f, cx0 = 0.f, cx1 = 0.f;

    // G-phase tiling: XCD-pinned weight panels. Dispatch round-robins blocks
    // over the 8 XCDs (xcd = b%8), so give each XCD a FIXED pair of nb panels
    // (4.7 MB immutable wc data -> stays resident in its 4 MB L2 across all
    // 16 steps; r10's nb=(b>>1)&15 scattered all 16 panels over every XCD).
    const int jG = b >> 3;
    const int nbG = ((b & 7) << 1) | (jG & 1);   // nb in {2*xcd, 2*xcd+1}
    const int kcG = (jG >> 1) & 7;
    const int mbG = (jG >> 4) & 1;
    const int m0G = mbG * 128, n0G = nbG * 128, k0G = kcG * KCHUNK;
    const int wmG = wv >> 1, wnG = wv & 1;
    const u16* gsrc0[8];       // start-of-chunk source pointers
    u16* gdst[8];
    #pragma unroll
    for (int q = 0; q < 8; ++q) {
        const int idx = ((q * 256 + t) & 511);
        const int row = idx >> 2;
        const int ko = (idx & 3) * 8;
        const int mat = q >> 1;
        const u16* gbase;
        if (mat == 0)      gbase = xcat_hi + (size_t)(m0G + row) * KTOT;
        else if (mat == 1) gbase = xcat_lo + (size_t)(m0G + row) * KTOT;
        else if (mat == 2) gbase = wc_hi + (size_t)(n0G + row) * KTOT;
        else               gbase = wc_lo + (size_t)(n0G + row) * KTOT;
        gsrc0[q] = gbase + k0G + ko;
        gdst[q] = &gsm[mat][row][ko];
    }

    // ---------- weight split phase (wc = [W_ih | W_hh] hi/lo, L3-direct) ----------
    {
        const int nchunk = 2048 * KTOT / 4;      // 2,359,296
        for (int c = b * 256 + t; c < nchunk; c += 65536) {
            const int j = c / (KTOT / 4);
            const int k = (c - j * (KTOT / 4)) * 4;
            float4 v;
            if (k < 4096) v = *(const float4*)&W_ih[(size_t)j * 4096 + k];
            else          v = *(const float4*)&W_hh[(size_t)j * 512 + (k - 4096)];
            float f[4] = {v.x, v.y, v.z, v.w};
            u64 hq = 0, lq = 0;
            #pragma unroll
            for (int i = 0; i < 4; ++i) {
                u16 hi = f2bf(f[i]);
                u16 lo = f2bf(f[i] - bf2f(hi));
                hq |= (u64)hi << (16 * i);
                lq |= (u64)lo << (16 * i);
            }
            const size_t o = (size_t)j * KTOT + k;
            st_l3_u64(&wc_hi[o], hq);
            st_l3_u64(&wc_lo[o], lq);
        }
    }
    // first wc read is in G(0), after the first grid barrier (race-free)

    for (int step = 0; step < NSTEP; ++step) {
        // ========== LSTM update from previous step's partials ==========
        if (step == 0) {
            const size_t o = (size_t)b * KTOT + 4096 + 2 * t;
            st_l3_u32(&xcat_hi[o], 0u);
            st_l3_u32(&xcat_lo[o], 0u);
        } else {
            const int u0 = 2 * t, u1 = 2 * t + 1;
            float gi0 = b_ih[u0] + b_hh[u0],             gi1 = b_ih[u1] + b_hh[u1];
            float gf0 = b_ih[HID + u0] + b_hh[HID + u0], gf1 = b_ih[HID + u1] + b_hh[HID + u1];
            float gg0 = b_ih[2*HID + u0] + b_hh[2*HID + u0], gg1 = b_ih[2*HID + u1] + b_hh[2*HID + u1];
            float go0 = b_ih[3*HID + u0] + b_hh[3*HID + u0], go1 = b_ih[3*HID + u1] + b_hh[3*HID + u1];
            const float* pb = part + (size_t)b * 2048;
            #pragma unroll
            for (int kc = 0; kc < SPLITK; ++kc) {
                const float* p = pb + (size_t)kc * (256 * 2048);
                float2 a = ld_l3_f32x2(p + u0);
                float2 c = ld_l3_f32x2(p + HID + u0);
                float2 d = ld_l3_f32x2(p + 2 * HID + u0);
                float2 e = ld_l3_f32x2(p + 3 * HID + u0);
                gi0 += a.x; gi1 += a.y;
                gf0 += c.x; gf1 += c.y;
                gg0 += d.x; gg1 += d.y;
                go0 += e.x; go1 += e.y;
            }
            float c0 = sigm(gf0) * cx0 + sigm(gi0) * tanhf(gg0);
            float c1 = sigm(gf1) * cx1 + sigm(gi1) * tanhf(gg1);
            float h0 = sigm(go0) * tanhf(c0);
            float h1 = sigm(go1) * tanhf(c1);
            cx0 = c0; cx1 = c1; hx0 = h0; hx1 = h1;
            u16 hh0 = f2bf(h0), hh1 = f2bf(h1);
            u16 hl0 = f2bf(h0 - bf2f(hh0)), hl1 = f2bf(h1 - bf2f(hh1));
            const size_t o = (size_t)b * KTOT + 4096 + 2 * t;
            st_l3_u32(&xcat_hi[o], (u32)hh0 | ((u32)hh1 << 16));
            st_l3_u32(&xcat_lo[o], (u32)hl0 | ((u32)hl1 << 16));
        }
        // ========== params: gp = tanh(Hx @ W_g^T + b_g) ==========
        float2 wg0 = *(const float2*)&W_g[2 * t];
        float2 wg1 = *(const float2*)&W_g[HID + 2 * t];
        float2 wg2 = *(const float2*)&W_g[2 * HID + 2 * t];
        float s0 = hx0 * wg0.x + hx1 * wg0.y;
        float s1 = hx0 * wg1.x + hx1 * wg1.y;
        float s2 = hx0 * wg2.x + hx1 * wg2.y;
        for (int off = 32; off; off >>= 1) {
            s0 += __shfl_xor(s0, off, 64);
            s1 += __shfl_xor(s1, off, 64);
            s2 += __shfl_xor(s2, off, 64);
        }
        __syncthreads();
        if (lane == 0) { red[wv * 3 + 0] = s0; red[wv * 3 + 1] = s1; red[wv * 3 + 2] = s2; }
        __syncthreads();
        s0 = red[0] + red[3] + red[6] + red[9];
        s1 = red[1] + red[4] + red[7] + red[10];
        s2 = red[2] + red[5] + red[8] + red[11];
        const float g0 = tanhf(s0 + b_g[0]);
        const float g1 = tanhf(s1 + b_g[1]);
        const float g2 = tanhf(s2 + b_g[2]);
        const float ad = fabsf(g2);
        const float ch = 127.5f * (g0 + 1.0f);
        const float cw = 127.5f * (g1 + 1.0f);
        const float dl = 4.0f * (1.0f - ad);
        const float gm = expf(1.0f - 2.0f * ad);
        const float ig = 1.0f / gm;
        const float coef = 1.0f / (3.14159265358979323846f * gm);

        // ========== glimpse phase 1: t1T[gw][h] = sum_w Fw[gw][w]*img[h][w] ==========
        const int fwr = t >> 2;              // gw row this thread fills
        const int fwc = (t & 3) * 8;         // col offset within 32-chunk
        const float rcw = cw + dl * ((float)fwr - 31.5f);
        float rsW = 0.f;

        const float* imgp = imgs + (size_t)(b * 2 + (step & 1)) * (IMG * IMG);
        int rowA[8], coA[8];
        float4 pf[8];
        #pragma unroll
        for (int q = 0; q < 8; ++q) {
            const int c = q * 256 + t;
            rowA[q] = c >> 3;
            coA[q]  = (c & 7) * 4;
            pf[q] = ld_nt_f32x4(&imgp[rowA[q] * IMG + coA[q]]);
        }
        f32x4 acc[4][4];
        #pragma unroll
        for (int mi = 0; mi < 4; ++mi)
            #pragma unroll
            for (int ni = 0; ni < 4; ++ni) acc[mi][ni] = (f32x4)(0.f);

        for (int ks = 0; ks < 8; ++ks) {
            __syncthreads();
            #pragma unroll
            for (int q = 0; q < 8; ++q) {
                float f[4] = {pf[q].x, pf[q].y, pf[q].z, pf[q].w};
                u16 hh[4], ll[4];
                #pragma unroll
                for (int j = 0; j < 4; ++j) {
                    hh[j] = f2bf(f[j]);
                    ll[j] = f2bf(f[j] - bf2f(hh[j]));
                }
                *(ushort4*)&AstH[rowA[q] * SP + coA[q]] = make_ushort4(hh[0], hh[1], hh[2], hh[3]);
                *(ushort4*)&AstL[rowA[q] * SP + coA[q]] = make_ushort4(ll[0], ll[1], ll[2], ll[3]);
            }
            {
                u16 hh[8], ll[8];
                #pragma unroll
                for (int j = 0; j < 8; ++j) {
                    float u = ((float)(ks * 32 + fwc + j) - rcw) * ig;
                    float val = coef / (1.0f + u * u);
                    rsW += val;
                    hh[j] = f2bf(val);
                    ll[j] = f2bf(val - bf2f(hh[j]));
                }
                *(ushort4*)&FwcH[fwr * SP + fwc]     = make_ushort4(hh[0], hh[1], hh[2], hh[3]);
                *(ushort4*)&FwcH[fwr * SP + fwc + 4] = make_ushort4(hh[4], hh[5], hh[6], hh[7]);
                *(ushort4*)&FwcL[fwr * SP + fwc]     = make_ushort4(ll[0], ll[1], ll[2], ll[3]);
                *(ushort4*)&FwcL[fwr * SP + fwc + 4] = make_ushort4(ll[4], ll[5], ll[6], ll[7]);
            }
            __syncthreads();
            if (ks < 7) {
                #pragma unroll
                for (int q = 0; q < 8; ++q)
                    pf[q] = ld_nt_f32x4(&imgp[rowA[q] * IMG + (ks + 1) * 32 + coA[q]]);
            }
            s16x8 ah[4], al[4], bh[4], bl[4];
            #pragma unroll
            for (int mi = 0; mi < 4; ++mi) {
                const int r = mi * 16 + fr;
                ah[mi] = *(const s16x8*)&FwcH[r * SP + kg * 8];
                al[mi] = *(const s16x8*)&FwcL[r * SP + kg * 8];
            }
            #pragma unroll
            for (int ni = 0; ni < 4; ++ni) {
                const int r = wv * 64 + ni * 16 + fr;
                bh[ni] = *(const s16x8*)&AstH[r * SP + kg * 8];
                bl[ni] = *(const s16x8*)&AstL[r * SP + kg * 8];
            }
            #pragma unroll
            for (int mi = 0; mi < 4; ++mi)
                #pragma unroll
                for (int ni = 0; ni < 4; ++ni) {
                    acc[mi][ni] = __builtin_amdgcn_mfma_f32_16x16x32_bf16(ah[mi], bh[ni], acc[mi][ni], 0, 0, 0);
                    acc[mi][ni] = __builtin_amdgcn_mfma_f32_16x16x32_bf16(ah[mi], bl[ni], acc[mi][ni], 0, 0, 0);
                    acc[mi][ni] = __builtin_amdgcn_mfma_f32_16x16x32_bf16(al[mi], bh[ni], acc[mi][ni], 0, 0, 0);
                }
        }
        // invW reduce (4 consecutive lanes per row) and scale accumulators
        rsW += __shfl_xor(rsW, 1, 64);
        rsW += __shfl_xor(rsW, 2, 64);
        if ((t & 3) == 0) invW[fwr] = 1.0f / (rsW + 1e-4f);
        __syncthreads();
        #pragma unroll
        for (int mi = 0; mi < 4; ++mi) {
            float w4[4];
            #pragma unroll
            for (int r = 0; r < 4; ++r) w4[r] = invW[mi * 16 + kg * 4 + r];
            #pragma unroll
            for (int ni = 0; ni < 4; ++ni)
                #pragma unroll
                for (int r = 0; r < 4; ++r) acc[mi][ni][r] *= w4[r];
        }

        // ========== glimpse phase 2: x[gh][gw] = invA[gh]*sum_h Fh[gh][h]*t1T[gw][h] ==========
        f32x4 xacc[4];
        #pragma unroll
        for (int ni = 0; ni < 4; ++ni) xacc[ni] = (f32x4)(0.f);
        const int fhr = t >> 2;              // gh row this thread fills
        const int fhc = (t & 3) * 16;        // col offset within 64-chunk
        const float rch = ch + dl * ((float)fhr - 31.5f);
        float rsA = 0.f;

        for (int p = 0; p < 4; ++p) {
            __syncthreads();
            #pragma unroll
            for (int blk = 0; blk < 4; ++blk) {
                u16 hh[4], ll[4];
                #pragma unroll
                for (int j = 0; j < 4; ++j) {
                    float u = ((float)(p * 64 + fhc + blk * 4 + j) - rch) * ig;
                    float val = coef / (1.0f + u * u);
                    rsA += val;
                    hh[j] = f2bf(val);
                    ll[j] = f2bf(val - bf2f(hh[j]));
                }
                *(ushort4*)&FhcH[fhr * TP + fhc + blk * 4] = make_ushort4(hh[0], hh[1], hh[2], hh[3]);
                *(ushort4*)&FhcL[fhr * TP + fhc + blk * 4] = make_ushort4(ll[0], ll[1], ll[2], ll[3]);
            }
            if (wv == p) {
                #pragma unroll
                for (int mi = 0; mi < 4; ++mi)
                    #pragma unroll
                    for (int ni = 0; ni < 4; ++ni)
                        #pragma unroll
                        for (int r = 0; r < 4; ++r) {
                            const int row = mi * 16 + kg * 4 + r;   // gw
                            const int col = ni * 16 + fr;           // local h
                            float v = acc[mi][ni][r];
                            u16 hv = f2bf(v);
                            t1TH[row * TP + col] = hv;
                            t1TL[row * TP + col] = f2bf(v - bf2f(hv));
                        }
            }
            __syncthreads();
            #pragma unroll
            for (int k2 = 0; k2 < 2; ++k2) {
                const int ra = wv * 16 + fr;
                s16x8 a2h = *(const s16x8*)&FhcH[ra * TP + k2 * 32 + kg * 8];
                s16x8 a2l = *(const s16x8*)&FhcL[ra * TP + k2 * 32 + kg * 8];
                #pragma unroll
                for (int ni = 0; ni < 4; ++ni) {
                    const int rb = ni * 16 + fr;
                    s16x8 b2h = *(const s16x8*)&t1TH[rb * TP + k2 * 32 + kg * 8];
                    s16x8 b2l = *(const s16x8*)&t1TL[rb * TP + k2 * 32 + kg * 8];
                    xacc[ni] = __builtin_amdgcn_mfma_f32_16x16x32_bf16(a2h, b2h, xacc[ni], 0, 0, 0);
                    xacc[ni] = __builtin_amdgcn_mfma_f32_16x16x32_bf16(a2h, b2l, xacc[ni], 0, 0, 0);
                    xacc[ni] = __builtin_amdgcn_mfma_f32_16x16x32_bf16(a2l, b2h, xacc[ni], 0, 0, 0);
                }
            }
        }
        // invA reduce; stage x tile to LDS as f32; pack & store L3-direct
        rsA += __shfl_xor(rsA, 1, 64);
        rsA += __shfl_xor(rsA, 2, 64);
        if ((t & 3) == 0) invA[fhr] = 1.0f / (rsA + 1e-4f);
        __syncthreads();   // also: all phase-2 LDS reads done -> xs overlay safe
        {
            float ia[4];
            #pragma unroll
            for (int r = 0; r < 4; ++r) ia[r] = invA[wv * 16 + kg * 4 + r];
            #pragma unroll
            for (int ni = 0; ni < 4; ++ni) {
                const int col = ni * 16 + fr;
                #pragma unroll
                for (int r = 0; r < 4; ++r)
                    xs[(wv * 16 + kg * 4 + r) * 66 + col] = xacc[ni][r] * ia[r];
            }
        }
        __syncthreads();
        {
            u16* xho = xcat_hi + (size_t)b * KTOT;
            u16* xlo = xcat_lo + (size_t)b * KTOT;
            #pragma unroll
            for (int pi = 0; pi < 8; ++pi) {
                const int idx = t * 8 + pi;          // u32-pair index in 64x64 tile
                const int row = idx >> 5;
                const int c2 = (idx & 31) * 2;
                float v0 = xs[row * 66 + c2];
                float v1 = xs[row * 66 + c2 + 1];
                u16 h0 = f2bf(v0), h1 = f2bf(v1);
                u16 l0 = f2bf(v0 - bf2f(h0)), l1 = f2bf(v1 - bf2f(h1));
                st_l3_u32(&xho[row * GSZ + c2], (u32)h0 | ((u32)h1 << 16));
                st_l3_u32(&xlo[row * GSZ + c2], (u32)l0 | ((u32)l1 << 16));
            }
        }

        // prefetch weight tiles only when wc is known-stable (after barrier 1)
        s16x8 gld[8];
        if (step > 0) {
            #pragma unroll
            for (int q = 4; q < 8; ++q) gld[q] = *(const s16x8*)(gsrc0[q]);
        }

        gridbar(bar, 2 * step + 1);

        // ================= G phase: gates GEMM (split-K) =================
        {
            const u16* srcs[8];
            #pragma unroll
            for (int q = 0; q < 8; ++q) srcs[q] = gsrc0[q];
            if (step == 0) {
                #pragma unroll
                for (int q = 4; q < 8; ++q) gld[q] = ld_l3_16(srcs[q]);  // wc via L3 (step 0)
            }
            #pragma unroll
            for (int q = 0; q < 4; ++q) gld[q] = ld_l3_16(srcs[q]);   // xcat: L3-direct

            f32x4 gacc[4][4];
            #pragma unroll
            for (int mi = 0; mi < 4; ++mi)
                #pragma unroll
                for (int ni = 0; ni < 4; ++ni) gacc[mi][ni] = (f32x4)(0.f);

            for (int ks = 0; ks < KSTEPS; ++ks) {
                __syncthreads();
                #pragma unroll
                for (int q = 0; q < 8; ++q) {
                    *(s16x8*)(gdst[q]) = gld[q];
                    srcs[q] += 32;
                }
                __syncthreads();
                if (ks + 1 < KSTEPS) {
                    #pragma unroll
                    for (int q = 0; q < 4; ++q) gld[q] = ld_l3_16(srcs[q]);       // xcat
                    #pragma unroll
                    for (int q = 4; q < 8; ++q) gld[q] = *(const s16x8*)(srcs[q]); // wc: L2-pinned
                }
                s16x8 ah[4], al[4], bh[4], bl[4];
                #pragma unroll
                for (int mi = 0; mi < 4; ++mi) {
                    const int r = wmG * 64 + mi * 16 + fr;
                    ah[mi] = *(const s16x8*)&gsm[0][r][kg * 8];
                    al[mi] = *(const s16x8*)&gsm[1][r][kg * 8];
                }
                #pragma unroll
                for (int ni = 0; ni < 4; ++ni) {
                    const int r = wnG * 64 + ni * 16 + fr;
                    bh[ni] = *(const s16x8*)&gsm[2][r][kg * 8];
                    bl[ni] = *(const s16x8*)&gsm[3][r][kg * 8];
                }
                #pragma unroll
                for (int mi = 0; mi < 4; ++mi)
                    #pragma unroll
                    for (int ni = 0; ni < 4; ++ni) {
                        gacc[mi][ni] = __builtin_amdgcn_mfma_f32_16x16x32_bf16(ah[mi], bh[ni], gacc[mi][ni], 0, 0, 0);
                        gacc[mi][ni] = __builtin_amdgcn_mfma_f32_16x16x32_bf16(ah[mi], bl[ni], gacc[mi][ni], 0, 0, 0);
                        gacc[mi][ni] = __builtin_amdgcn_mfma_f32_16x16x32_bf16(al[mi], bh[ni], gacc[mi][ni], 0, 0, 0);
                    }
            }

            float* pp = part + ((size_t)kcG << 19);   // L3-direct stores
            #pragma unroll
            for (int mi = 0; mi < 4; ++mi) {
                const int mbase = m0G + wmG * 64 + mi * 16 + kg * 4;
                #pragma unroll
                for (int ni = 0; ni < 4; ++ni) {
                    const int col = n0G + wnG * 64 + ni * 16 + fr;
                    #pragma unroll
                    for (int r = 0; r < 4; ++r)
                        st_l3_f32(&pp[(size_t)(mbase + r) * 2048 + col], gacc[mi][ni][r]);
                }
            }
        }
        gridbar(bar, 2 * step + 2);
    }

    // ================= final LSTM update -> out =================
    {
        const int u0 = 2 * t, u1 = 2 * t + 1;
        float gi0 = b_ih[u0] + b_hh[u0],             gi1 = b_ih[u1] + b_hh[u1];
        float gf0 = b_ih[HID + u0] + b_hh[HID + u0], gf1 = b_ih[HID + u1] + b_hh[HID + u1];
        float gg0 = b_ih[2*HID + u0] + b_hh[2*HID + u0], gg1 = b_ih[2*HID + u1] + b_hh[2*HID + u1];
        float go0 = b_ih[3*HID + u0] + b_hh[3*HID + u0], go1 = b_ih[3*HID + u1] + b_hh[3*HID + u1];
        const float* pb = part + (size_t)b * 2048;
        #pragma unroll
        for (int kc = 0; kc < SPLITK; ++kc) {
            const float* p = pb + (size_t)kc * (256 * 2048);
            float2 a = ld_l3_f32x2(p + u0);
            float2 c = ld_l3_f32x2(p + HID + u0);
            float2 d = ld_l3_f32x2(p + 2 * HID + u0);
            float2 e = ld_l3_f32x2(p + 3 * HID + u0);
            gi0 += a.x; gi1 += a.y;
            gf0 += c.x; gf1 += c.y;
            gg0 += d.x; gg1 += d.y;
            go0 += e.x; go1 += e.y;
        }
        float c0 = sigm(gf0) * cx0 + sigm(gi0) * tanhf(gg0);
        float c1 = sigm(gf1) * cx1 + sigm(gi1) * tanhf(gg1);
        float h0 = sigm(go0) * tanhf(c0);
        float h1 = sigm(go1) * tanhf(c1);
        out[(size_t)b * HID + u0] = h0;
        out[(size_t)b * HID + u1] = h1;
    }
}

extern "C" void kernel_launch(void* const* d_in, const int* in_sizes, int n_in,
                              void* d_out, int out_size, void* d_ws, size_t ws_size,
                              hipStream_t stream) {
    const float* imgs = (const float*)d_in[0];
    const float* W_ih = (const float*)d_in[1];
    const float* W_hh = (const float*)d_in[2];
    const float* b_ih = (const float*)d_in[3];
    const float* b_hh = (const float*)d_in[4];
    const float* W_g  = (const float*)d_in[5];
    const float* b_g  = (const float*)d_in[6];
    float* out = (float*)d_out;

    char* w = (char*)d_ws;
    int* bar       = (int*)w;    w += 4096;                     // 257 ints used
    u16* xcat_hi   = (u16*)w;    w += (size_t)NB * KTOT * 2;
    u16* xcat_lo   = (u16*)w;    w += (size_t)NB * KTOT * 2;
    u16* wc_hi     = (u16*)w;    w += (size_t)2048 * KTOT * 2;
    u16* wc_lo     = (u16*)w;    w += (size_t)2048 * KTOT * 2;
    float* part    = (float*)w;  w += (size_t)SPLITK * NB * 2048 * 4;

    // barrier state must start at 0 every call (ws is poisoned once, not re-poisoned)
    hipMemsetAsync(bar, 0, 4096, stream);

    k_all<<<NB, 256, 0, stream>>>(imgs, W_ih, W_hh, b_ih, b_hh, W_g, b_g,
                                  bar, wc_hi, wc_lo, xcat_hi, xcat_lo, part, out);
}